// Round 2
// baseline (764.135 us; speedup 1.0000x reference)
//
#include <hip/hip_runtime.h>

#define N_NODES 50000
#define N_EDGES 800000

typedef __attribute__((ext_vector_type(8))) short short8;
typedef __attribute__((ext_vector_type(4))) float f32x4;

// float -> bf16 (round-to-nearest-even), bit pattern in a short.
__device__ __forceinline__ short bf16_rne(float f) {
  unsigned u = __float_as_uint(f);
  unsigned r = (u + 0x7FFFu + ((u >> 16) & 1u)) >> 16;
  return (short)r;
}

// ---------------------------------------------------------------------------
// Kernel A: per-node projections (unchanged from round 1).
// NP[n][0:64]   = n_feat[n] @ Wa_d   NP[n][64:128] = n_feat[n] @ Wa_s
// NP[n][128:192]= n_feat[n] @ Wt_d   NP[n][192:256]= n_feat[n] @ Wt_s
// NP[n][256:320]= n_feat[n] @ W_e
// ---------------------------------------------------------------------------
__global__ __launch_bounds__(64) void node_proj(
    const float* __restrict__ n_feat, const float* __restrict__ W_a,
    const float* __restrict__ W_T, const float* __restrict__ W_e,
    float* __restrict__ NP) {
  __shared__ float sN[16 * 128];
  const int lane = threadIdx.x;
  const int n0 = blockIdx.x * 16;

  float4* sN4 = (float4*)sN;
  const float4* nf4 = (const float4*)(n_feat + (size_t)n0 * 128);
  #pragma unroll
  for (int t = 0; t < 8; ++t) sN4[t * 64 + lane] = nf4[t * 64 + lane];
  __syncthreads();

  float acc[5][16];
  #pragma unroll
  for (int q = 0; q < 5; ++q)
    #pragma unroll
    for (int i = 0; i < 16; ++i) acc[q][i] = 0.f;

  for (int k = 0; k < 128; ++k) {
    float w0 = W_a[k * 64 + lane];
    float w1 = W_a[(192 + k) * 64 + lane];
    float w2 = W_T[k * 64 + lane];
    float w3 = W_T[(192 + k) * 64 + lane];
    float w4 = W_e[k * 64 + lane];
    #pragma unroll
    for (int i = 0; i < 16; ++i) {
      float nv = sN[i * 128 + k];
      acc[0][i] = __builtin_fmaf(nv, w0, acc[0][i]);
      acc[1][i] = __builtin_fmaf(nv, w1, acc[1][i]);
      acc[2][i] = __builtin_fmaf(nv, w2, acc[2][i]);
      acc[3][i] = __builtin_fmaf(nv, w3, acc[3][i]);
      acc[4][i] = __builtin_fmaf(nv, w4, acc[4][i]);
    }
  }
  #pragma unroll
  for (int i = 0; i < 16; ++i)
    #pragma unroll
    for (int q = 0; q < 5; ++q)
      NP[(size_t)(n0 + i) * 320 + q * 64 + lane] = acc[q][i];
}

// ---------------------------------------------------------------------------
// Kernel B: bf16-MFMA edge GEMM (e_feat @ [Wa_e|Wt_e|W_ee]) + fused epilogue.
// Wave = 32 edges x 192 cols via mfma_f32_16x16x32_bf16:
//   A frag: lane holds e_feat[ebase + rt*16 + (lane&15)][kt*32 + (lane>>4)*8 + j]
//   B frag: lane holds W[kt*32 + (lane>>4)*8 + j][ct*16 + (lane&15)]
//   D frag: col = lane&15, row(edge) = (lane>>4)*4 + reg   [m89-verified]
// W^T staged in LDS as bf16 [C=192][k=64], XOR-swizzled (kgroup ^= C&7) so the
// stride-128B ds_read_b128 is 2-way (free) instead of 16-way.
// No segment_max: softmax is shift-invariant and logits are O(10) -> exp safe.
// ---------------------------------------------------------------------------
__global__ __launch_bounds__(256) void edge_pass_mfma(
    const float* __restrict__ e_feat, const int* __restrict__ src,
    const int* __restrict__ dst, const float* __restrict__ W_a,
    const float* __restrict__ W_T, const float* __restrict__ W_ee,
    const float* __restrict__ prelu_a, const float* __restrict__ NP,
    float* __restrict__ denom, float* __restrict__ numer,
    float* __restrict__ out_e) {
  __shared__ short sWT[192 * 64];  // 24 KB, [C][k] bf16, swizzled
  const int tid = threadIdx.x;
  const int lane = tid & 63;
  const int wid = tid >> 6;

  // Stage W^T -> bf16, swizzled: elem (C,k) at C*64 + ((k>>3)^(C&7))*8 + (k&7).
  // Write pairs (k even) as one 4B store.
  for (int idx = tid; idx < 192 * 32; idx += 256) {
    int C = idx >> 5;
    int k = (idx & 31) * 2;
    float f0, f1;
    if (C < 64)       { f0 = W_a[(128 + k) * 64 + C];        f1 = W_a[(129 + k) * 64 + C]; }
    else if (C < 128) { f0 = W_T[(128 + k) * 64 + (C - 64)]; f1 = W_T[(129 + k) * 64 + (C - 64)]; }
    else              { f0 = W_ee[k * 64 + (C - 128)];       f1 = W_ee[(k + 1) * 64 + (C - 128)]; }
    unsigned pack = ((unsigned)(unsigned short)bf16_rne(f0)) |
                    (((unsigned)(unsigned short)bf16_rne(f1)) << 16);
    int sidx = C * 64 + (((k >> 3) ^ (C & 7)) << 3) + (k & 7);
    *(unsigned*)(&sWT[sidx]) = pack;
  }
  __syncthreads();
  const float pa = prelu_a[0];

  const int row = lane & 15;   // A-row / B-col within tile
  const int q   = lane >> 4;   // quarter-wave = k-group / D-row-group

  const int ngroups = N_EDGES / 128;
  for (int g = blockIdx.x; g < ngroups; g += gridDim.x) {
    const int ebase = g * 128 + wid * 32;

    // --- A fragments: 2 row-tiles x 2 K-tiles, global->reg->bf16 ---
    short8 afrag[2][2];
    #pragma unroll
    for (int rt = 0; rt < 2; ++rt)
      #pragma unroll
      for (int kt = 0; kt < 2; ++kt) {
        const float* p = e_feat + (size_t)(ebase + rt * 16 + row) * 64 + kt * 32 + q * 8;
        float4 v0 = *(const float4*)p;
        float4 v1 = *(const float4*)(p + 4);
        short8 a;
        a[0] = bf16_rne(v0.x); a[1] = bf16_rne(v0.y);
        a[2] = bf16_rne(v0.z); a[3] = bf16_rne(v0.w);
        a[4] = bf16_rne(v1.x); a[5] = bf16_rne(v1.y);
        a[6] = bf16_rne(v1.z); a[7] = bf16_rne(v1.w);
        afrag[rt][kt] = a;
      }

    // --- MFMA: acc[rt][ct], ct 0..3 = Wa_e cols, 4..7 = Wt_e, 8..11 = W_ee ---
    f32x4 acc[2][12];
    #pragma unroll
    for (int rt = 0; rt < 2; ++rt)
      #pragma unroll
      for (int ct = 0; ct < 12; ++ct) acc[rt][ct] = (f32x4){0.f, 0.f, 0.f, 0.f};

    #pragma unroll
    for (int kt = 0; kt < 2; ++kt)
      #pragma unroll
      for (int ct = 0; ct < 12; ++ct) {
        int C = ct * 16 + row;
        int kg = (kt * 4 + q) ^ (C & 7);
        short8 b = *(const short8*)(&sWT[C * 64 + kg * 8]);
        acc[0][ct] = __builtin_amdgcn_mfma_f32_16x16x32_bf16(afrag[0][kt], b, acc[0][ct], 0, 0, 0);
        acc[1][ct] = __builtin_amdgcn_mfma_f32_16x16x32_bf16(afrag[1][kt], b, acc[1][ct], 0, 0, 0);
      }

    // --- Epilogue: per (edge row, reg) walk the D layout ---
    #pragma unroll
    for (int rt = 0; rt < 2; ++rt) {
      #pragma unroll
      for (int r = 0; r < 4; ++r) {
        int e = ebase + rt * 16 + q * 4 + r;
        int d = dst[e], s = src[e];
        const float* NPd = NP + (size_t)d * 320;
        const float* NPs = NP + (size_t)s * 320;
        float* dn = denom + (size_t)d * 64;
        float* nm = numer + (size_t)d * 64;
        float* oe = out_e + (size_t)e * 64;
        #pragma unroll
        for (int ct = 0; ct < 4; ++ct) {
          int c = ct * 16 + row;
          float la = NPd[c] + acc[rt][ct][r] + NPs[64 + c];
          float lg = la >= 0.f ? la : pa * la;
          float ex = __expf(lg);
          float un = NPd[128 + c] + acc[rt][4 + ct][r] + NPs[192 + c];
          atomicAdd(dn + c, ex);
          atomicAdd(nm + c, ex * un);
          oe[c] = NPs[256 + c] + NPd[256 + c] + acc[rt][8 + ct][r];
        }
      }
    }
  }
}

// Kernel C: new_n_feat = denom>0 ? num/denom + b_T : 0.
__global__ __launch_bounds__(256) void node_final(
    const float* __restrict__ denom, const float* __restrict__ numer,
    const float* __restrict__ b_T, float* __restrict__ out_n) {
  int t = blockIdx.x * 256 + threadIdx.x;
  if (t >= N_NODES * 64) return;
  float dn = denom[t];
  out_n[t] = dn > 0.f ? numer[t] / dn + b_T[t & 63] : 0.f;
}

extern "C" void kernel_launch(void* const* d_in, const int* in_sizes, int n_in,
                              void* d_out, int out_size, void* d_ws, size_t ws_size,
                              hipStream_t stream) {
  const float* n_feat  = (const float*)d_in[0];
  const float* e_feat  = (const float*)d_in[1];
  const int*   src     = (const int*)d_in[2];
  const int*   dst     = (const int*)d_in[3];
  const float* W_a     = (const float*)d_in[4];
  const float* W_T     = (const float*)d_in[5];
  const float* b_T     = (const float*)d_in[6];
  const float* W_e     = (const float*)d_in[7];
  const float* W_ee    = (const float*)d_in[8];
  const float* prelu_a = (const float*)d_in[9];

  float* out_n = (float*)d_out;
  float* out_e = out_n + (size_t)N_NODES * 64;

  // ws: NP (50000*320 f32 = 64 MB) | denom (12.8 MB) | numer (12.8 MB)
  float* NP    = (float*)d_ws;
  float* denom = NP + (size_t)N_NODES * 320;
  float* numer = denom + (size_t)N_NODES * 64;

  hipMemsetAsync(denom, 0, (size_t)N_NODES * 64 * 2 * sizeof(float), stream);
  node_proj<<<N_NODES / 16, 64, 0, stream>>>(n_feat, W_a, W_T, W_e, NP);
  edge_pass_mfma<<<2048, 256, 0, stream>>>(e_feat, src, dst, W_a, W_T, W_ee,
                                           prelu_a, NP, denom, numer, out_e);
  node_final<<<(N_NODES * 64 + 255) / 256, 256, 0, stream>>>(denom, numer, b_T, out_n);
}